// Round 18
// baseline (114.986 us; speedup 1.0000x reference)
//
#include <hip/hip_runtime.h>

typedef unsigned short u16;
typedef unsigned u32;
typedef __bf16 bf16x8 __attribute__((ext_vector_type(8)));
typedef float f32x4 __attribute__((ext_vector_type(4)));
typedef u16 u16x8 __attribute__((ext_vector_type(8)));
typedef u16 u16x4v __attribute__((ext_vector_type(4)));

#define D_MODEL 1024
#define SEQ 2048
#define NB 2
#define NH 16

#define MFMA(a, b, c) __builtin_amdgcn_mfma_f32_16x16x32_bf16(a, b, c, 0, 0, 0)

__device__ __forceinline__ u16 f2bf(float f) {
  unsigned u = __builtin_bit_cast(unsigned, f);
  u += 0x7FFFu + ((u >> 16) & 1u);   // round-to-nearest-even
  return (u16)(u >> 16);
}

__device__ __forceinline__ u16 f2bf_hw(float f) {
  return __builtin_bit_cast(u16, (__bf16)f);
}

__device__ __forceinline__ bf16x8 ld8(const u16* p) {
  return __builtin_bit_cast(bf16x8, *(const u16x8*)p);
}

typedef const __attribute__((address_space(1))) unsigned gu32;
typedef __attribute__((address_space(3))) unsigned lu32;
__device__ __forceinline__ void gload16(const u16* g, u16* l) {
  // async global->LDS, 16B per lane; LDS dest = wave-uniform base + lane*16
  __builtin_amdgcn_global_load_lds((gu32*)g, (lu32*)l, 16, 0, 0);
}

#define WAITV8 asm volatile("s_waitcnt vmcnt(8)" ::: "memory")
#define WAITV4 asm volatile("s_waitcnt vmcnt(4)" ::: "memory")
#define WAITV0 asm volatile("s_waitcnt vmcnt(0)" ::: "memory")
#define BARRIER __builtin_amdgcn_s_barrier()
#define SB0 __builtin_amdgcn_sched_barrier(0)

// ---------------------------------------------------------------------------
// Kernel 0: fp32 -> bf16 convert of X and all four weight matrices.
// ---------------------------------------------------------------------------
__global__ __launch_bounds__(256) void convert_kernel(
    const float* __restrict__ X, const float* __restrict__ Wq,
    const float* __restrict__ Wk, const float* __restrict__ Wv,
    const float* __restrict__ Wo, u16* __restrict__ Xb, u16* __restrict__ Wb)
{
  const int NX4 = 1024 * 1024;
  const int NW4 = 256 * 1024;
  const int TOT = NX4 + 4 * NW4;
  for (int i = blockIdx.x * 256 + threadIdx.x; i < TOT; i += gridDim.x * 256) {
    const float* src;
    u16* dst;
    if (i < NX4) {
      src = X + (size_t)i * 4;
      dst = Xb + (size_t)i * 4;
    } else {
      int j = i - NX4;
      int w = j >> 18;
      int off = j & (NW4 - 1);
      const float* ws = (w == 0) ? Wq : (w == 1) ? Wk : (w == 2) ? Wv : Wo;
      src = ws + (size_t)off * 4;
      dst = Wb + (size_t)j * 4;
    }
    float4 v = *(const float4*)src;
    u16x4v o = { f2bf(v.x), f2bf(v.y), f2bf(v.z), f2bf(v.w) };
    *(u16x4v*)dst = o;
  }
}

// ---------------------------------------------------------------------------
// Kernel 1: QKV GEMM, 256x256 tile, 8 waves, BK=32, 4-buffer LDS rotation,
// one raw s_barrier per phase, counted vmcnt(8), compact-region XCD swizzle
// (unchanged from R14 — measured best).
// ---------------------------------------------------------------------------
__global__ __launch_bounds__(512, 2) void qkv8w(
    const u16* __restrict__ A, const u16* __restrict__ B,
    u16* __restrict__ Qb, u16* __restrict__ Kb, u16* __restrict__ Vt)
{
  __shared__ u16 As[4][8192];   // 4 x 16 KB
  __shared__ u16 Bs[4][8192];   // 4 x 16 KB  -> 128 KB total
  const int t = threadIdx.x;
  const int lane = t & 63, w = t >> 6;
  const int wm = w >> 2, wn = w & 3;

  // compact-region XCD swizzle: XCD = lid%8 -> 4x6 block region
  const int lid = blockIdx.x + 16 * blockIdx.y;   // 0..191
  const int xcd = lid & 7;
  const int k = lid >> 3;                          // 0..23
  const int bx = (xcd >> 1) * 4 + (k & 3);         // 0..15
  const int by = (xcd & 1) * 6 + (k >> 2);         // 0..11

  const int m0 = bx * 256;
  const int kg = lane >> 4, lr = lane & 15;
  const int rp = lr >> 1, hf = lr & 1;
  const int xr = (((hf * 4 + kg) ^ rp) * 8);

  const int lc = (lane & 7) ^ (lane >> 3);
  const int ghalf = lc >> 2, kc = lc & 3;
  const int n0 = by * 256;

  f32x4 acc[8][4] = {};

  auto stage = [&](int buf, int kt) {
    #pragma unroll
    for (int j = 0; j < 2; ++j) {
      int g = (j * 64 + w * 8 + (lane >> 3)) * 2 + ghalf;
      gload16(&A[(size_t)(m0 + g) * 1024 + kt * 32 + kc * 8],
              &As[buf][(j * 8 + w) * 512]);
      gload16(&B[(size_t)(n0 + g) * 1024 + kt * 32 + kc * 8],
              &Bs[buf][(j * 8 + w) * 512]);
    }
  };

  auto phase = [&](int buf) {
    const u16* as = &As[buf][0];
    const u16* bs = &Bs[buf][0];
    bf16x8 a[8], b[4];
    #pragma unroll
    for (int mi = 0; mi < 8; ++mi)
      a[mi] = ld8(&as[(wm * 64 + mi * 8 + rp) * 64 + xr]);
    #pragma unroll
    for (int ni = 0; ni < 4; ++ni)
      b[ni] = ld8(&bs[(wn * 32 + ni * 8 + rp) * 64 + xr]);
    __builtin_amdgcn_s_setprio(1);
    #pragma unroll
    for (int mi = 0; mi < 8; ++mi)
      #pragma unroll
      for (int ni = 0; ni < 4; ++ni)
        acc[mi][ni] = MFMA(a[mi], b[ni], acc[mi][ni]);
    __builtin_amdgcn_s_setprio(0);
  };

  stage(0, 0);
  stage(1, 1);
  stage(2, 2);

  for (int tt = 0; tt < 28; tt += 4) {
    #pragma unroll
    for (int q = 0; q < 4; ++q) {
      const int kt = tt + q;
      WAITV8;
      BARRIER;
      SB0;
      stage((q + 3) & 3, kt + 3);
      phase(q);
    }
  }
  WAITV8; BARRIER; SB0; stage(3, 31); phase(0);
  WAITV8; BARRIER; SB0; phase(1);
  WAITV4; BARRIER; SB0; phase(2);
  WAITV0; BARRIER; SB0; phase(3);

  // epilogue: scatter to Q/K/V.  C/D frag: row = kg*4+i, col = lr.
  const int zby = by >> 2;              // 0=Q, 1=K, 2=V
  const int nl0 = (by & 3) * 256;
  const float scl = (zby == 0) ? 0.125f : 1.0f; // fold 1/sqrt(d_k) into Q
  #pragma unroll
  for (int mi = 0; mi < 8; ++mi) {
    #pragma unroll
    for (int ni = 0; ni < 4; ++ni) {
      int m = m0 + wm * 128 + mi * 16 + kg * 4;
      int nl = nl0 + wn * 64 + ni * 16 + lr;
      int bb = m >> 11, s = m & (SEQ - 1);
      int h = nl >> 6, dk = nl & 63;
      size_t bh = (size_t)(bb * NH + h);
      if (zby == 2) {
        u16x4v v = { f2bf(acc[mi][ni][0]), f2bf(acc[mi][ni][1]),
                     f2bf(acc[mi][ni][2]), f2bf(acc[mi][ni][3]) };
        *(u16x4v*)&Vt[(bh * 64 + dk) * SEQ + s] = v;
      } else {
        u16* dst = (zby == 0 ? Qb : Kb) + ((bh * SEQ + s) * 64 + dk);
        #pragma unroll
        for (int i = 0; i < 4; ++i) dst[(size_t)i * 64] = f2bf(acc[mi][ni][i] * scl);
      }
    }
  }
}

// ---------------------------------------------------------------------------
// Kernel 3: output projection — qkv8w schedule: 128x128 tile, 8 waves,
// BK=64, 16 phases, 4-buffer LDS rotation, counted vmcnt(8) (unchanged
// from R16 — measured improvement).
// ---------------------------------------------------------------------------
__global__ __launch_bounds__(512, 2) void oproj8w(
    const u16* __restrict__ A, const u16* __restrict__ B,
    float* __restrict__ out)
{
  __shared__ u16 As[4][8192];   // 4 x 16 KB (128 rows x 64 K, chunk-XOR swz)
  __shared__ u16 Bs[4][8192];
  const int t = threadIdx.x;
  const int lane = t & 63, w = t >> 6;
  const int wm = w >> 2, wn = w & 3;      // 2 x 4 wave grid
  const int m0 = blockIdx.x * 128;
  const int n0 = blockIdx.y * 128;
  const int kg = lane >> 4, lr = lane & 15;

  const int srow = lane >> 3;
  const int lc = (lane & 7) ^ srow;

  f32x4 acc[4][2] = {};

  auto stage = [&](int buf, int kt) {
    #pragma unroll
    for (int j = 0; j < 2; ++j) {
      int r = (j * 8 + w) * 8 + srow;     // 0..127
      gload16(&A[(size_t)(m0 + r) * 1024 + kt * 64 + lc * 8],
              &As[buf][(j * 8 + w) * 512]);
      gload16(&B[(size_t)(n0 + r) * 1024 + kt * 64 + lc * 8],
              &Bs[buf][(j * 8 + w) * 512]);
    }
  };

  auto phase = [&](int buf) {
    const u16* as = &As[buf][0];
    const u16* bs = &Bs[buf][0];
    #pragma unroll
    for (int kh = 0; kh < 2; ++kh) {
      bf16x8 a[4], b[2];
      #pragma unroll
      for (int mi = 0; mi < 4; ++mi) {
        int row = wm * 64 + mi * 16 + lr;
        int ch = (kh * 4 + kg) ^ (row & 7);
        a[mi] = ld8(&as[row * 64 + ch * 8]);
      }
      #pragma unroll
      for (int ni = 0; ni < 2; ++ni) {
        int row = wn * 32 + ni * 16 + lr;
        int ch = (kh * 4 + kg) ^ (row & 7);
        b[ni] = ld8(&bs[row * 64 + ch * 8]);
      }
      __builtin_amdgcn_s_setprio(1);
      #pragma unroll
      for (int mi = 0; mi < 4; ++mi)
        #pragma unroll
        for (int ni = 0; ni < 2; ++ni)
          acc[mi][ni] = MFMA(a[mi], b[ni], acc[mi][ni]);
      __builtin_amdgcn_s_setprio(0);
    }
  };

  stage(0, 0);
  stage(1, 1);
  stage(2, 2);

  for (int tt = 0; tt < 12; tt += 4) {
    #pragma unroll
    for (int q = 0; q < 4; ++q) {
      const int kt = tt + q;
      WAITV8;
      BARRIER;
      SB0;
      stage((q + 3) & 3, kt + 3);
      phase(q);
    }
  }
  WAITV8; BARRIER; SB0; stage(3, 15); phase(0);
  WAITV8; BARRIER; SB0; phase(1);
  WAITV4; BARRIER; SB0; phase(2);
  WAITV0; BARRIER; SB0; phase(3);

  #pragma unroll
  for (int mi = 0; mi < 4; ++mi)
    #pragma unroll
    for (int ni = 0; ni < 2; ++ni) {
      int m = m0 + wm * 64 + mi * 16 + kg * 4;
      int n = n0 + wn * 32 + ni * 16 + lr;
      #pragma unroll
      for (int i = 0; i < 4; ++i)
        out[(size_t)(m + i) * D_MODEL + n] = acc[mi][ni][i];
    }
}

// ---------------------------------------------------------------------------
// Kernel 2: causal flash attention — QBLK=128 via TWO q-subtiles per wave.
// K/V fragment LDS reads are q-independent (address depends only on lane),
// so 8 K-reads + 8 V-reads feed BOTH subtiles' MFMAs from registers:
// LDS ops per 16 q-rows drop 22 -> 14 (the measured binding pipe).
// 4 waves x 32 q-rows; grid (32,16) = 512 blocks = 2/CU; LDS 48 KB.
// Balance: qt2 = y<8 ? y : 23-y (co-resident pair {y,y+8} sums to 34 iters).
// Mask only kt >= ntile-2 (earlier tiles have kv_max < q0). Per-fragment
// layouts identical to the proven R10/R16 body. XCD pin id%8 = bh%8.
// ---------------------------------------------------------------------------
__global__ __launch_bounds__(256) void attn_kernel(
    const u16* __restrict__ Qb, const u16* __restrict__ Kb,
    const u16* __restrict__ Vt, u16* __restrict__ AO)
{
  __shared__ u16 Ks[2][64 * 64];   // 16 KB
  __shared__ u16 Vs[2][64 * 64];   // 16 KB  (Vs[d][kv], chunk-swizzled)
  __shared__ u16 Ps[4][32 * 64];   // 16 KB: per wave 32 q-rows, chunk8^(row&7)
  const int t = threadIdx.x;
  const int bh = blockIdx.x;       // head -> XCD = bh % 8
  const int y = blockIdx.y;        // 0..15
  const int qt2 = (y < 8) ? y : 23 - y;   // co-resident pair sums to 34 iters
  const int lane = t & 63, wv = t >> 6;
  const int kg = lane >> 4, lr = lane & 15;
  const int r8 = lane >> 3, c = lane & 7;
  const int b = bh >> 4, h = bh & (NH - 1);

  auto stage = [&](int buf, int kv0) {
    #pragma unroll
    for (int i = 0; i < 2; ++i) {
      int s = wv * 2 + i;
      int row = s * 8 + r8;                       // 0..63
      int sc = c ^ (row & 7);                     // pre-swizzled source chunk
      gload16(&Kb[((size_t)bh * SEQ + kv0 + row) * 64 + sc * 8], &Ks[buf][s * 512]);
      gload16(&Vt[((size_t)bh * 64 + row) * SEQ + kv0 + sc * 8], &Vs[buf][s * 512]);
    }
  };

  const int ntile = 2 * qt2 + 2;
  const int q0 = qt2 * 128;
  const int qgA = q0 + wv * 32 + lr;      // subtile A q row (global)
  const int qgB = qgA + 16;               // subtile B

  const size_t qrowA = (size_t)bh * SEQ + qgA;
  bf16x8 aqA0 = ld8(&Qb[qrowA * 64 + kg * 8]);        // Q pre-scaled by 0.125
  bf16x8 aqA1 = ld8(&Qb[qrowA * 64 + 32 + kg * 8]);
  bf16x8 aqB0 = ld8(&Qb[(qrowA + 16) * 64 + kg * 8]);
  bf16x8 aqB1 = ld8(&Qb[(qrowA + 16) * 64 + 32 + kg * 8]);

  f32x4 ofA[4] = {}, ofB[4] = {};
  float rsA = 0.f, rsB = 0.f;

  stage(0, 0);
  int cur = 0;
  u16* ps = &Ps[wv][0];
  const int pwrA = lr * 64;               // P row base, subtile A (row = lr)
  const int pwrB = (16 + lr) * 64;        // subtile B (row&7 identical)
  const int ch0 = kg ^ (lr & 7);          // chunk for k/kv 8kg..8kg+7
  const int ch1 = (4 + kg) ^ (lr & 7);

  for (int kt = 0; kt < ntile; ++kt) {
    const int kv0 = kt * 64;
    __syncthreads();               // drains staging of buf[cur]
    if (kt + 1 < ntile) stage(cur ^ 1, (kt + 1) * 64);

    // K fragments ONCE (q-independent addresses), reused by both subtiles
    const u16* kb = &Ks[cur][0];
    bf16x8 kf0[4], kf1[4];
    #pragma unroll
    for (int ct = 0; ct < 4; ++ct) {
      kf0[ct] = ld8(&kb[(ct * 16 + lr) * 64 + ch0 * 8]);
      kf1[ct] = ld8(&kb[(ct * 16 + lr) * 64 + ch1 * 8]);
    }

    // scores (swapped): S^T = K @ Q^T ; lane holds q=lr, kv=ct*16+kg*4+i
    f32x4 scA[4] = {}, scB[4] = {};
    __builtin_amdgcn_s_setprio(1);
    #pragma unroll
    for (int ct = 0; ct < 4; ++ct) {
      scA[ct] = MFMA(kf0[ct], aqA0, scA[ct]);
      scA[ct] = MFMA(kf1[ct], aqA1, scA[ct]);
      scB[ct] = MFMA(kf0[ct], aqB0, scB[ct]);
      scB[ct] = MFMA(kf1[ct], aqB1, scB[ct]);
    }
    __builtin_amdgcn_s_setprio(0);

    // max-free softmax: P = exp(S), masked -> 0; packed b64 P-writes
    const bool domask = (kt >= ntile - 2);
    #pragma unroll
    for (int ct = 0; ct < 4; ++ct) {
      #pragma unroll
      for (int i = 0; i < 4; ++i) {
        float e = __expf(scA[ct][i]);
        if (domask && (kv0 + ct * 16 + kg * 4 + i > qgA)) e = 0.f;
        scA[ct][i] = e;
        rsA += e;
      }
      u16x4v pw = { f2bf_hw(scA[ct][0]), f2bf_hw(scA[ct][1]),
                    f2bf_hw(scA[ct][2]), f2bf_hw(scA[ct][3]) };
      *(u16x4v*)&ps[pwrA + (((2 * ct + (kg >> 1)) ^ (lr & 7)) * 8 + (kg & 1) * 4)] = pw;
    }
    #pragma unroll
    for (int ct = 0; ct < 4; ++ct) {
      #pragma unroll
      for (int i = 0; i < 4; ++i) {
        float e = __expf(scB[ct][i]);
        if (domask && (kv0 + ct * 16 + kg * 4 + i > qgB)) e = 0.f;
        scB[ct][i] = e;
        rsB += e;
      }
      u16x4v pw = { f2bf_hw(scB[ct][0]), f2bf_hw(scB[ct][1]),
                    f2bf_hw(scB[ct][2]), f2bf_hw(scB[ct][3]) };
      *(u16x4v*)&ps[pwrB + (((2 * ct + (kg >> 1)) ^ (lr & 7)) * 8 + (kg & 1) * 4)] = pw;
    }

    bf16x8 paA0 = ld8(&ps[pwrA + ch0 * 8]);
    bf16x8 paA1 = ld8(&ps[pwrA + ch1 * 8]);
    bf16x8 paB0 = ld8(&ps[pwrB + ch0 * 8]);
    bf16x8 paB1 = ld8(&ps[pwrB + ch1 * 8]);

    // V fragments ONCE, reused by both subtiles
    const u16* vb = &Vs[cur][0];
    bf16x8 vf0[4], vf1[4];
    #pragma unroll
    for (int vt = 0; vt < 4; ++vt) {
      vf0[vt] = ld8(&vb[(vt * 16 + lr) * 64 + ch0 * 8]);
      vf1[vt] = ld8(&vb[(vt * 16 + lr) * 64 + ch1 * 8]);
    }

    __builtin_amdgcn_s_setprio(1);
    #pragma unroll
    for (int vt = 0; vt < 4; ++vt) {
      ofA[vt] = MFMA(paA0, vf0[vt], ofA[vt]);
      ofA[vt] = MFMA(paA1, vf1[vt], ofA[vt]);
      ofB[vt] = MFMA(paB0, vf0[vt], ofB[vt]);
      ofB[vt] = MFMA(paB1, vf1[vt], ofB[vt]);
    }
    __builtin_amdgcn_s_setprio(0);
    cur ^= 1;
  }

  // per-lane partials for q = lr (subtile-local); reduce across kg-groups
  rsA += __shfl_xor(rsA, 16, 64);
  rsA += __shfl_xor(rsA, 32, 64);
  rsB += __shfl_xor(rsB, 16, 64);
  rsB += __shfl_xor(rsB, 32, 64);

  // of[vt][i] is q-local = kg*4+i -> denominator from lane kg*4+i
  #pragma unroll
  for (int i = 0; i < 4; ++i) {
    float invA = 1.0f / __shfl(rsA, kg * 4 + i, 64);
    float invB = 1.0f / __shfl(rsB, kg * 4 + i, 64);
    int sA = q0 + wv * 32 + kg * 4 + i;
    size_t baseA = ((size_t)(b * SEQ + sA)) * D_MODEL + h * 64 + lr;
    size_t baseB = ((size_t)(b * SEQ + sA + 16)) * D_MODEL + h * 64 + lr;
    #pragma unroll
    for (int vt = 0; vt < 4; ++vt) {
      AO[baseA + vt * 16] = f2bf_hw(ofA[vt][i] * invA);
      AO[baseB + vt * 16] = f2bf_hw(ofB[vt][i] * invB);
    }
  }
}

// ---------------------------------------------------------------------------
extern "C" void kernel_launch(void* const* d_in, const int* in_sizes, int n_in,
                              void* d_out, int out_size, void* d_ws, size_t ws_size,
                              hipStream_t stream) {
  const float* X  = (const float*)d_in[0];
  const float* Wq = (const float*)d_in[1];
  const float* Wk = (const float*)d_in[2];
  const float* Wv = (const float*)d_in[3];
  const float* Wo = (const float*)d_in[4];
  float* out = (float*)d_out;

  u16* Xb = (u16*)d_ws;
  u16* Wb = Xb + (size_t)4096 * 1024;
  u16* Qb = Wb + (size_t)4096 * 1024;
  u16* Kb = Qb + (size_t)4096 * 1024;
  u16* Vt = Kb + (size_t)4096 * 1024;
  u16* AO = Vt + (size_t)4096 * 1024;

  convert_kernel<<<2048, 256, 0, stream>>>(X, Wq, Wk, Wv, Wo, Xb, Wb);
  qkv8w<<<dim3(16, 12), 512, 0, stream>>>(Xb, Wb, Qb, Kb, Vt);
  attn_kernel<<<dim3(32, 16), 256, 0, stream>>>(Qb, Kb, Vt, AO);
  oproj8w<<<dim3(32, 8), 512, 0, stream>>>(AO, Wb + (size_t)3 * 1024 * 1024, out);
}

// Round 19
// 106.488 us; speedup vs baseline: 1.0798x; 1.0798x over previous
//
#include <hip/hip_runtime.h>

typedef unsigned short u16;
typedef unsigned u32;
typedef __bf16 bf16x8 __attribute__((ext_vector_type(8)));
typedef float f32x4 __attribute__((ext_vector_type(4)));
typedef u16 u16x8 __attribute__((ext_vector_type(8)));
typedef u16 u16x4v __attribute__((ext_vector_type(4)));

#define D_MODEL 1024
#define SEQ 2048
#define NB 2
#define NH 16

#define MFMA(a, b, c) __builtin_amdgcn_mfma_f32_16x16x32_bf16(a, b, c, 0, 0, 0)

__device__ __forceinline__ u16 f2bf(float f) {
  unsigned u = __builtin_bit_cast(unsigned, f);
  u += 0x7FFFu + ((u >> 16) & 1u);   // round-to-nearest-even
  return (u16)(u >> 16);
}

__device__ __forceinline__ u16 f2bf_hw(float f) {
  return __builtin_bit_cast(u16, (__bf16)f);
}

__device__ __forceinline__ bf16x8 ld8(const u16* p) {
  return __builtin_bit_cast(bf16x8, *(const u16x8*)p);
}

typedef const __attribute__((address_space(1))) unsigned gu32;
typedef __attribute__((address_space(3))) unsigned lu32;
__device__ __forceinline__ void gload16(const u16* g, u16* l) {
  // async global->LDS, 16B per lane; LDS dest = wave-uniform base + lane*16
  __builtin_amdgcn_global_load_lds((gu32*)g, (lu32*)l, 16, 0, 0);
}

#define WAITV8 asm volatile("s_waitcnt vmcnt(8)" ::: "memory")
#define WAITV4 asm volatile("s_waitcnt vmcnt(4)" ::: "memory")
#define WAITV0 asm volatile("s_waitcnt vmcnt(0)" ::: "memory")
#define BARRIER __builtin_amdgcn_s_barrier()
#define SB0 __builtin_amdgcn_sched_barrier(0)

// ---------------------------------------------------------------------------
// Kernel 0: fp32 -> bf16 convert of X and all four weight matrices.
// ---------------------------------------------------------------------------
__global__ __launch_bounds__(256) void convert_kernel(
    const float* __restrict__ X, const float* __restrict__ Wq,
    const float* __restrict__ Wk, const float* __restrict__ Wv,
    const float* __restrict__ Wo, u16* __restrict__ Xb, u16* __restrict__ Wb)
{
  const int NX4 = 1024 * 1024;
  const int NW4 = 256 * 1024;
  const int TOT = NX4 + 4 * NW4;
  for (int i = blockIdx.x * 256 + threadIdx.x; i < TOT; i += gridDim.x * 256) {
    const float* src;
    u16* dst;
    if (i < NX4) {
      src = X + (size_t)i * 4;
      dst = Xb + (size_t)i * 4;
    } else {
      int j = i - NX4;
      int w = j >> 18;
      int off = j & (NW4 - 1);
      const float* ws = (w == 0) ? Wq : (w == 1) ? Wk : (w == 2) ? Wv : Wo;
      src = ws + (size_t)off * 4;
      dst = Wb + (size_t)j * 4;
    }
    float4 v = *(const float4*)src;
    u16x4v o = { f2bf(v.x), f2bf(v.y), f2bf(v.z), f2bf(v.w) };
    *(u16x4v*)dst = o;
  }
}

// ---------------------------------------------------------------------------
// Kernel 1: QKV GEMM, 256x256 tile, 8 waves, BK=32, 4-buffer LDS rotation,
// one raw s_barrier per phase, counted vmcnt(8), compact-region XCD swizzle
// (unchanged from R14 — measured best). Q pre-scale folds log2(e) for the
// exp2-domain softmax.
// ---------------------------------------------------------------------------
__global__ __launch_bounds__(512, 2) void qkv8w(
    const u16* __restrict__ A, const u16* __restrict__ B,
    u16* __restrict__ Qb, u16* __restrict__ Kb, u16* __restrict__ Vt)
{
  __shared__ u16 As[4][8192];   // 4 x 16 KB
  __shared__ u16 Bs[4][8192];   // 4 x 16 KB  -> 128 KB total
  const int t = threadIdx.x;
  const int lane = t & 63, w = t >> 6;
  const int wm = w >> 2, wn = w & 3;

  // compact-region XCD swizzle: XCD = lid%8 -> 4x6 block region
  const int lid = blockIdx.x + 16 * blockIdx.y;   // 0..191
  const int xcd = lid & 7;
  const int k = lid >> 3;                          // 0..23
  const int bx = (xcd >> 1) * 4 + (k & 3);         // 0..15
  const int by = (xcd & 1) * 6 + (k >> 2);         // 0..11

  const int m0 = bx * 256;
  const int kg = lane >> 4, lr = lane & 15;
  const int rp = lr >> 1, hf = lr & 1;
  const int xr = (((hf * 4 + kg) ^ rp) * 8);

  const int lc = (lane & 7) ^ (lane >> 3);
  const int ghalf = lc >> 2, kc = lc & 3;
  const int n0 = by * 256;

  f32x4 acc[8][4] = {};

  auto stage = [&](int buf, int kt) {
    #pragma unroll
    for (int j = 0; j < 2; ++j) {
      int g = (j * 64 + w * 8 + (lane >> 3)) * 2 + ghalf;
      gload16(&A[(size_t)(m0 + g) * 1024 + kt * 32 + kc * 8],
              &As[buf][(j * 8 + w) * 512]);
      gload16(&B[(size_t)(n0 + g) * 1024 + kt * 32 + kc * 8],
              &Bs[buf][(j * 8 + w) * 512]);
    }
  };

  auto phase = [&](int buf) {
    const u16* as = &As[buf][0];
    const u16* bs = &Bs[buf][0];
    bf16x8 a[8], b[4];
    #pragma unroll
    for (int mi = 0; mi < 8; ++mi)
      a[mi] = ld8(&as[(wm * 64 + mi * 8 + rp) * 64 + xr]);
    #pragma unroll
    for (int ni = 0; ni < 4; ++ni)
      b[ni] = ld8(&bs[(wn * 32 + ni * 8 + rp) * 64 + xr]);
    __builtin_amdgcn_s_setprio(1);
    #pragma unroll
    for (int mi = 0; mi < 8; ++mi)
      #pragma unroll
      for (int ni = 0; ni < 4; ++ni)
        acc[mi][ni] = MFMA(a[mi], b[ni], acc[mi][ni]);
    __builtin_amdgcn_s_setprio(0);
  };

  stage(0, 0);
  stage(1, 1);
  stage(2, 2);

  for (int tt = 0; tt < 28; tt += 4) {
    #pragma unroll
    for (int q = 0; q < 4; ++q) {
      const int kt = tt + q;
      WAITV8;
      BARRIER;
      SB0;
      stage((q + 3) & 3, kt + 3);
      phase(q);
    }
  }
  WAITV8; BARRIER; SB0; stage(3, 31); phase(0);
  WAITV8; BARRIER; SB0; phase(1);
  WAITV4; BARRIER; SB0; phase(2);
  WAITV0; BARRIER; SB0; phase(3);

  // epilogue: scatter to Q/K/V.  C/D frag: row = kg*4+i, col = lr.
  const int zby = by >> 2;              // 0=Q, 1=K, 2=V
  const int nl0 = (by & 3) * 256;
  // Q scale: 1/sqrt(64) * log2(e)  (softmax computed in exp2 domain)
  const float scl = (zby == 0) ? 0.125f * 1.442695040888963f : 1.0f;
  #pragma unroll
  for (int mi = 0; mi < 8; ++mi) {
    #pragma unroll
    for (int ni = 0; ni < 4; ++ni) {
      int m = m0 + wm * 128 + mi * 16 + kg * 4;
      int nl = nl0 + wn * 64 + ni * 16 + lr;
      int bb = m >> 11, s = m & (SEQ - 1);
      int h = nl >> 6, dk = nl & 63;
      size_t bh = (size_t)(bb * NH + h);
      if (zby == 2) {
        u16x4v v = { f2bf(acc[mi][ni][0]), f2bf(acc[mi][ni][1]),
                     f2bf(acc[mi][ni][2]), f2bf(acc[mi][ni][3]) };
        *(u16x4v*)&Vt[(bh * 64 + dk) * SEQ + s] = v;
      } else {
        u16* dst = (zby == 0 ? Qb : Kb) + ((bh * SEQ + s) * 64 + dk);
        #pragma unroll
        for (int i = 0; i < 4; ++i) dst[(size_t)i * 64] = f2bf(acc[mi][ni][i] * scl);
      }
    }
  }
}

// ---------------------------------------------------------------------------
// Kernel 3: output projection — qkv8w schedule: 128x128 tile, 8 waves,
// BK=64, 16 phases, 4-buffer LDS rotation, counted vmcnt(8) (unchanged
// from R16 — measured improvement).
// ---------------------------------------------------------------------------
__global__ __launch_bounds__(512, 2) void oproj8w(
    const u16* __restrict__ A, const u16* __restrict__ B,
    float* __restrict__ out)
{
  __shared__ u16 As[4][8192];   // 4 x 16 KB (128 rows x 64 K, chunk-XOR swz)
  __shared__ u16 Bs[4][8192];
  const int t = threadIdx.x;
  const int lane = t & 63, w = t >> 6;
  const int wm = w >> 2, wn = w & 3;      // 2 x 4 wave grid
  const int m0 = blockIdx.x * 128;
  const int n0 = blockIdx.y * 128;
  const int kg = lane >> 4, lr = lane & 15;

  const int srow = lane >> 3;
  const int lc = (lane & 7) ^ srow;

  f32x4 acc[4][2] = {};

  auto stage = [&](int buf, int kt) {
    #pragma unroll
    for (int j = 0; j < 2; ++j) {
      int r = (j * 8 + w) * 8 + srow;     // 0..127
      gload16(&A[(size_t)(m0 + r) * 1024 + kt * 64 + lc * 8],
              &As[buf][(j * 8 + w) * 512]);
      gload16(&B[(size_t)(n0 + r) * 1024 + kt * 64 + lc * 8],
              &Bs[buf][(j * 8 + w) * 512]);
    }
  };

  auto phase = [&](int buf) {
    const u16* as = &As[buf][0];
    const u16* bs = &Bs[buf][0];
    #pragma unroll
    for (int kh = 0; kh < 2; ++kh) {
      bf16x8 a[4], b[2];
      #pragma unroll
      for (int mi = 0; mi < 4; ++mi) {
        int row = wm * 64 + mi * 16 + lr;
        int ch = (kh * 4 + kg) ^ (row & 7);
        a[mi] = ld8(&as[row * 64 + ch * 8]);
      }
      #pragma unroll
      for (int ni = 0; ni < 2; ++ni) {
        int row = wn * 32 + ni * 16 + lr;
        int ch = (kh * 4 + kg) ^ (row & 7);
        b[ni] = ld8(&bs[row * 64 + ch * 8]);
      }
      __builtin_amdgcn_s_setprio(1);
      #pragma unroll
      for (int mi = 0; mi < 4; ++mi)
        #pragma unroll
        for (int ni = 0; ni < 2; ++ni)
          acc[mi][ni] = MFMA(a[mi], b[ni], acc[mi][ni]);
      __builtin_amdgcn_s_setprio(0);
    }
  };

  stage(0, 0);
  stage(1, 1);
  stage(2, 2);

  for (int tt = 0; tt < 12; tt += 4) {
    #pragma unroll
    for (int q = 0; q < 4; ++q) {
      const int kt = tt + q;
      WAITV8;
      BARRIER;
      SB0;
      stage((q + 3) & 3, kt + 3);
      phase(q);
    }
  }
  WAITV8; BARRIER; SB0; stage(3, 15); phase(0);
  WAITV8; BARRIER; SB0; phase(1);
  WAITV4; BARRIER; SB0; phase(2);
  WAITV0; BARRIER; SB0; phase(3);

  #pragma unroll
  for (int mi = 0; mi < 4; ++mi)
    #pragma unroll
    for (int ni = 0; ni < 2; ++ni) {
      int m = m0 + wm * 64 + mi * 16 + kg * 4;
      int n = n0 + wn * 32 + ni * 16 + lr;
      #pragma unroll
      for (int i = 0; i < 4; ++i)
        out[(size_t)(m + i) * D_MODEL + n] = acc[mi][ni][i];
    }
}

// ---------------------------------------------------------------------------
// Kernel 2: causal flash attention — R17 state (measured best total 98.7us),
// SINGLE CHANGE: exp2-domain softmax (log2e pre-folded into Q by qkv8w;
// __expf -> exp2f deletes 16 v_mul from each iteration's VALU chain).
// Swapped-QK^T, packed b64 P-writes, scalar row-sum, balanced qt remap,
// KVBLK=64, double-buffered K/V via global_load_lds + XOR swizzle, 40 KB
// LDS (4 blocks/CU), XCD pin id%8 = bh%8.
// ---------------------------------------------------------------------------
__global__ __launch_bounds__(256) void attn_kernel(
    const u16* __restrict__ Qb, const u16* __restrict__ Kb,
    const u16* __restrict__ Vt, u16* __restrict__ AO)
{
  __shared__ u16 Ks[2][64 * 64];   // 16 KB
  __shared__ u16 Vs[2][64 * 64];   // 16 KB  (Vs[d][kv], chunk-swizzled)
  __shared__ u16 Ps[4][16 * 64];   // 8 KB, chunk8 ^ (row&7) swizzle
  const int t = threadIdx.x;
  const int bh = blockIdx.x;       // head -> XCD = bh % 8
  const int y = blockIdx.y;
  // balanced remap: family {y0, y0+8, y0+16, y0+24} -> qt {y0,15-y0,16+y0,31-y0}
  const int qt = (y < 8) ? y : (y < 16) ? (23 - y) : (y < 24) ? y : (55 - y);
  const int lane = t & 63, wv = t >> 6;
  const int kg = lane >> 4, lr = lane & 15;
  const int r8 = lane >> 3, c = lane & 7;
  const int b = bh >> 4, h = bh & (NH - 1);

  auto stage = [&](int buf, int kv0) {
    #pragma unroll
    for (int i = 0; i < 2; ++i) {
      int s = wv * 2 + i;
      int row = s * 8 + r8;                       // 0..63
      int sc = c ^ (row & 7);                     // pre-swizzled source chunk
      gload16(&Kb[((size_t)bh * SEQ + kv0 + row) * 64 + sc * 8], &Ks[buf][s * 512]);
      gload16(&Vt[((size_t)bh * 64 + row) * SEQ + kv0 + sc * 8], &Vs[buf][s * 512]);
    }
  };

  const int ntile = qt + 1;
  const int q0 = qt * 64;
  const int qg = q0 + wv * 16 + lr;   // this lane's q row (global)

  const size_t qrow = (size_t)bh * SEQ + qg;
  bf16x8 aq0 = ld8(&Qb[qrow * 64 + kg * 8]);        // Q pre-scaled 0.125*log2e
  bf16x8 aq1 = ld8(&Qb[qrow * 64 + 32 + kg * 8]);

  f32x4 of[4] = {};
  float rs = 0.f;

  stage(0, 0);
  int cur = 0;
  u16* ps = &Ps[wv][0];
  const int pwr = lr * 64;            // P row base (row = q local = lr)
  const int ch0 = kg ^ (lr & 7);      // chunk for k/kv 8kg..8kg+7
  const int ch1 = (4 + kg) ^ (lr & 7);

  for (int kt = 0; kt < ntile; ++kt) {
    const int kv0 = kt * 64;
    __syncthreads();               // drains staging of buf[cur]
    if (kt + 1 < ntile) stage(cur ^ 1, (kt + 1) * 64);

    // scores (swapped): S^T[kv][q] = K @ Q^T ; lane holds q=lr, kv=ct*16+kg*4+i
    const u16* kb = &Ks[cur][0];
    f32x4 sc4[4] = {};
    __builtin_amdgcn_s_setprio(1);
    #pragma unroll
    for (int ct = 0; ct < 4; ++ct) {
      sc4[ct] = MFMA(ld8(&kb[(ct * 16 + lr) * 64 + ch0 * 8]), aq0, sc4[ct]);
      sc4[ct] = MFMA(ld8(&kb[(ct * 16 + lr) * 64 + ch1 * 8]), aq1, sc4[ct]);
    }
    __builtin_amdgcn_s_setprio(0);

    // max-free softmax in exp2 domain: P = 2^S, masked -> 0; b64 P-writes
    const bool domask = (kt == ntile - 1);
    #pragma unroll
    for (int ct = 0; ct < 4; ++ct) {
      #pragma unroll
      for (int i = 0; i < 4; ++i) {
        float e = exp2f(sc4[ct][i]);
        if (domask && (kv0 + ct * 16 + kg * 4 + i > qg)) e = 0.f;
        sc4[ct][i] = e;
        rs += e;
      }
      u16x4v pw = { f2bf_hw(sc4[ct][0]), f2bf_hw(sc4[ct][1]),
                    f2bf_hw(sc4[ct][2]), f2bf_hw(sc4[ct][3]) };
      // kv_local = ct*16+kg*4 -> chunk8 = 2ct+(kg>>1), offset (kg&1)*4
      *(u16x4v*)&ps[pwr + (((2 * ct + (kg >> 1)) ^ (lr & 7)) * 8 + (kg & 1) * 4)] = pw;
    }

    bf16x8 pa0 = ld8(&ps[pwr + ch0 * 8]);
    bf16x8 pa1 = ld8(&ps[pwr + ch1 * 8]);

    // PV: A = P rows q, B = Vs rows d (Vs[d][kv]) -> C row=q(kg*4+i), col=d(lr)
    const u16* vb = &Vs[cur][0];
    __builtin_amdgcn_s_setprio(1);
    #pragma unroll
    for (int vt = 0; vt < 4; ++vt) {
      of[vt] = MFMA(pa0, ld8(&vb[(vt * 16 + lr) * 64 + ch0 * 8]), of[vt]);
      of[vt] = MFMA(pa1, ld8(&vb[(vt * 16 + lr) * 64 + ch1 * 8]), of[vt]);
    }
    __builtin_amdgcn_s_setprio(0);
    cur ^= 1;
  }

  // rs: per-lane partial for q = lr; reduce across the 4 kg-groups
  rs += __shfl_xor(rs, 16, 64);
  rs += __shfl_xor(rs, 32, 64);

  // of[vt][i] is q = kg*4+i -> fetch that q's denominator from lane kg*4+i
  #pragma unroll
  for (int i = 0; i < 4; ++i) {
    float inv = 1.0f / __shfl(rs, kg * 4 + i, 64);
    int s = q0 + wv * 16 + kg * 4 + i;
    size_t base = ((size_t)(b * SEQ + s)) * D_MODEL + h * 64 + lr;
    #pragma unroll
    for (int vt = 0; vt < 4; ++vt)
      AO[base + vt * 16] = f2bf_hw(of[vt][i] * inv);
  }
}

// ---------------------------------------------------------------------------
extern "C" void kernel_launch(void* const* d_in, const int* in_sizes, int n_in,
                              void* d_out, int out_size, void* d_ws, size_t ws_size,
                              hipStream_t stream) {
  const float* X  = (const float*)d_in[0];
  const float* Wq = (const float*)d_in[1];
  const float* Wk = (const float*)d_in[2];
  const float* Wv = (const float*)d_in[3];
  const float* Wo = (const float*)d_in[4];
  float* out = (float*)d_out;

  u16* Xb = (u16*)d_ws;
  u16* Wb = Xb + (size_t)4096 * 1024;
  u16* Qb = Wb + (size_t)4096 * 1024;
  u16* Kb = Qb + (size_t)4096 * 1024;
  u16* Vt = Kb + (size_t)4096 * 1024;
  u16* AO = Vt + (size_t)4096 * 1024;

  convert_kernel<<<2048, 256, 0, stream>>>(X, Wq, Wk, Wv, Wo, Xb, Wb);
  qkv8w<<<dim3(16, 12), 512, 0, stream>>>(Xb, Wb, Qb, Kb, Vt);
  attn_kernel<<<dim3(32, 32), 256, 0, stream>>>(Qb, Kb, Vt, AO);
  oproj8w<<<dim3(32, 8), 512, 0, stream>>>(AO, Wb + (size_t)3 * 1024 * 1024, out);
}

// Round 20
// 104.664 us; speedup vs baseline: 1.0986x; 1.0174x over previous
//
#include <hip/hip_runtime.h>

typedef unsigned short u16;
typedef unsigned u32;
typedef __bf16 bf16x8 __attribute__((ext_vector_type(8)));
typedef float f32x4 __attribute__((ext_vector_type(4)));
typedef u16 u16x8 __attribute__((ext_vector_type(8)));
typedef u16 u16x4v __attribute__((ext_vector_type(4)));

#define D_MODEL 1024
#define SEQ 2048
#define NB 2
#define NH 16

#define MFMA(a, b, c) __builtin_amdgcn_mfma_f32_16x16x32_bf16(a, b, c, 0, 0, 0)

__device__ __forceinline__ u16 f2bf(float f) {
  unsigned u = __builtin_bit_cast(unsigned, f);
  u += 0x7FFFu + ((u >> 16) & 1u);   // round-to-nearest-even
  return (u16)(u >> 16);
}

__device__ __forceinline__ u16 f2bf_hw(float f) {
  return __builtin_bit_cast(u16, (__bf16)f);
}

__device__ __forceinline__ bf16x8 ld8(const u16* p) {
  return __builtin_bit_cast(bf16x8, *(const u16x8*)p);
}

typedef const __attribute__((address_space(1))) unsigned gu32;
typedef __attribute__((address_space(3))) unsigned lu32;
__device__ __forceinline__ void gload16(const u16* g, u16* l) {
  // async global->LDS, 16B per lane; LDS dest = wave-uniform base + lane*16
  __builtin_amdgcn_global_load_lds((gu32*)g, (lu32*)l, 16, 0, 0);
}

#define WAITV8 asm volatile("s_waitcnt vmcnt(8)" ::: "memory")
#define WAITV4 asm volatile("s_waitcnt vmcnt(4)" ::: "memory")
#define WAITV0 asm volatile("s_waitcnt vmcnt(0)" ::: "memory")
#define BARRIER __builtin_amdgcn_s_barrier()
#define SB0 __builtin_amdgcn_sched_barrier(0)

// ---------------------------------------------------------------------------
// Kernel 0: fp32 -> bf16 convert of X and all four weight matrices.
// ---------------------------------------------------------------------------
__global__ __launch_bounds__(256) void convert_kernel(
    const float* __restrict__ X, const float* __restrict__ Wq,
    const float* __restrict__ Wk, const float* __restrict__ Wv,
    const float* __restrict__ Wo, u16* __restrict__ Xb, u16* __restrict__ Wb)
{
  const int NX4 = 1024 * 1024;
  const int NW4 = 256 * 1024;
  const int TOT = NX4 + 4 * NW4;
  for (int i = blockIdx.x * 256 + threadIdx.x; i < TOT; i += gridDim.x * 256) {
    const float* src;
    u16* dst;
    if (i < NX4) {
      src = X + (size_t)i * 4;
      dst = Xb + (size_t)i * 4;
    } else {
      int j = i - NX4;
      int w = j >> 18;
      int off = j & (NW4 - 1);
      const float* ws = (w == 0) ? Wq : (w == 1) ? Wk : (w == 2) ? Wv : Wo;
      src = ws + (size_t)off * 4;
      dst = Wb + (size_t)j * 4;
    }
    float4 v = *(const float4*)src;
    u16x4v o = { f2bf(v.x), f2bf(v.y), f2bf(v.z), f2bf(v.w) };
    *(u16x4v*)dst = o;
  }
}

// ---------------------------------------------------------------------------
// Kernel 1: QKV GEMM, 256x256 tile, 8 waves, BK=32, 4-buffer LDS rotation,
// one raw s_barrier per phase, counted vmcnt(8), compact-region XCD swizzle
// (unchanged from R14 — measured best). Q pre-scale folds log2(e) for the
// exp2-domain softmax.
// ---------------------------------------------------------------------------
__global__ __launch_bounds__(512, 2) void qkv8w(
    const u16* __restrict__ A, const u16* __restrict__ B,
    u16* __restrict__ Qb, u16* __restrict__ Kb, u16* __restrict__ Vt)
{
  __shared__ u16 As[4][8192];   // 4 x 16 KB
  __shared__ u16 Bs[4][8192];   // 4 x 16 KB  -> 128 KB total
  const int t = threadIdx.x;
  const int lane = t & 63, w = t >> 6;
  const int wm = w >> 2, wn = w & 3;

  // compact-region XCD swizzle: XCD = lid%8 -> 4x6 block region
  const int lid = blockIdx.x + 16 * blockIdx.y;   // 0..191
  const int xcd = lid & 7;
  const int k = lid >> 3;                          // 0..23
  const int bx = (xcd >> 1) * 4 + (k & 3);         // 0..15
  const int by = (xcd & 1) * 6 + (k >> 2);         // 0..11

  const int m0 = bx * 256;
  const int kg = lane >> 4, lr = lane & 15;
  const int rp = lr >> 1, hf = lr & 1;
  const int xr = (((hf * 4 + kg) ^ rp) * 8);

  const int lc = (lane & 7) ^ (lane >> 3);
  const int ghalf = lc >> 2, kc = lc & 3;
  const int n0 = by * 256;

  f32x4 acc[8][4] = {};

  auto stage = [&](int buf, int kt) {
    #pragma unroll
    for (int j = 0; j < 2; ++j) {
      int g = (j * 64 + w * 8 + (lane >> 3)) * 2 + ghalf;
      gload16(&A[(size_t)(m0 + g) * 1024 + kt * 32 + kc * 8],
              &As[buf][(j * 8 + w) * 512]);
      gload16(&B[(size_t)(n0 + g) * 1024 + kt * 32 + kc * 8],
              &Bs[buf][(j * 8 + w) * 512]);
    }
  };

  auto phase = [&](int buf) {
    const u16* as = &As[buf][0];
    const u16* bs = &Bs[buf][0];
    bf16x8 a[8], b[4];
    #pragma unroll
    for (int mi = 0; mi < 8; ++mi)
      a[mi] = ld8(&as[(wm * 64 + mi * 8 + rp) * 64 + xr]);
    #pragma unroll
    for (int ni = 0; ni < 4; ++ni)
      b[ni] = ld8(&bs[(wn * 32 + ni * 8 + rp) * 64 + xr]);
    __builtin_amdgcn_s_setprio(1);
    #pragma unroll
    for (int mi = 0; mi < 8; ++mi)
      #pragma unroll
      for (int ni = 0; ni < 4; ++ni)
        acc[mi][ni] = MFMA(a[mi], b[ni], acc[mi][ni]);
    __builtin_amdgcn_s_setprio(0);
  };

  stage(0, 0);
  stage(1, 1);
  stage(2, 2);

  for (int tt = 0; tt < 28; tt += 4) {
    #pragma unroll
    for (int q = 0; q < 4; ++q) {
      const int kt = tt + q;
      WAITV8;
      BARRIER;
      SB0;
      stage((q + 3) & 3, kt + 3);
      phase(q);
    }
  }
  WAITV8; BARRIER; SB0; stage(3, 31); phase(0);
  WAITV8; BARRIER; SB0; phase(1);
  WAITV4; BARRIER; SB0; phase(2);
  WAITV0; BARRIER; SB0; phase(3);

  // epilogue: scatter to Q/K/V.  C/D frag: row = kg*4+i, col = lr.
  const int zby = by >> 2;              // 0=Q, 1=K, 2=V
  const int nl0 = (by & 3) * 256;
  // Q scale: 1/sqrt(64) * log2(e)  (softmax computed in exp2 domain)
  const float scl = (zby == 0) ? 0.125f * 1.442695040888963f : 1.0f;
  #pragma unroll
  for (int mi = 0; mi < 8; ++mi) {
    #pragma unroll
    for (int ni = 0; ni < 4; ++ni) {
      int m = m0 + wm * 128 + mi * 16 + kg * 4;
      int nl = nl0 + wn * 64 + ni * 16 + lr;
      int bb = m >> 11, s = m & (SEQ - 1);
      int h = nl >> 6, dk = nl & 63;
      size_t bh = (size_t)(bb * NH + h);
      if (zby == 2) {
        u16x4v v = { f2bf(acc[mi][ni][0]), f2bf(acc[mi][ni][1]),
                     f2bf(acc[mi][ni][2]), f2bf(acc[mi][ni][3]) };
        *(u16x4v*)&Vt[(bh * 64 + dk) * SEQ + s] = v;
      } else {
        u16* dst = (zby == 0 ? Qb : Kb) + ((bh * SEQ + s) * 64 + dk);
        #pragma unroll
        for (int i = 0; i < 4; ++i) dst[(size_t)i * 64] = f2bf(acc[mi][ni][i] * scl);
      }
    }
  }
}

// ---------------------------------------------------------------------------
// Kernel 3: output projection — qkv8w schedule: 128x128 tile, 8 waves,
// BK=64, 16 phases, 4-buffer LDS rotation, counted vmcnt(8) (unchanged
// from R16 — measured improvement).
// ---------------------------------------------------------------------------
__global__ __launch_bounds__(512, 2) void oproj8w(
    const u16* __restrict__ A, const u16* __restrict__ B,
    float* __restrict__ out)
{
  __shared__ u16 As[4][8192];   // 4 x 16 KB (128 rows x 64 K, chunk-XOR swz)
  __shared__ u16 Bs[4][8192];
  const int t = threadIdx.x;
  const int lane = t & 63, w = t >> 6;
  const int wm = w >> 2, wn = w & 3;      // 2 x 4 wave grid
  const int m0 = blockIdx.x * 128;
  const int n0 = blockIdx.y * 128;
  const int kg = lane >> 4, lr = lane & 15;

  const int srow = lane >> 3;
  const int lc = (lane & 7) ^ srow;

  f32x4 acc[4][2] = {};

  auto stage = [&](int buf, int kt) {
    #pragma unroll
    for (int j = 0; j < 2; ++j) {
      int r = (j * 8 + w) * 8 + srow;     // 0..127
      gload16(&A[(size_t)(m0 + r) * 1024 + kt * 64 + lc * 8],
              &As[buf][(j * 8 + w) * 512]);
      gload16(&B[(size_t)(n0 + r) * 1024 + kt * 64 + lc * 8],
              &Bs[buf][(j * 8 + w) * 512]);
    }
  };

  auto phase = [&](int buf) {
    const u16* as = &As[buf][0];
    const u16* bs = &Bs[buf][0];
    #pragma unroll
    for (int kh = 0; kh < 2; ++kh) {
      bf16x8 a[4], b[2];
      #pragma unroll
      for (int mi = 0; mi < 4; ++mi) {
        int row = wm * 64 + mi * 16 + lr;
        int ch = (kh * 4 + kg) ^ (row & 7);
        a[mi] = ld8(&as[row * 64 + ch * 8]);
      }
      #pragma unroll
      for (int ni = 0; ni < 2; ++ni) {
        int row = wn * 32 + ni * 16 + lr;
        int ch = (kh * 4 + kg) ^ (row & 7);
        b[ni] = ld8(&bs[row * 64 + ch * 8]);
      }
      __builtin_amdgcn_s_setprio(1);
      #pragma unroll
      for (int mi = 0; mi < 4; ++mi)
        #pragma unroll
        for (int ni = 0; ni < 2; ++ni)
          acc[mi][ni] = MFMA(a[mi], b[ni], acc[mi][ni]);
      __builtin_amdgcn_s_setprio(0);
    }
  };

  stage(0, 0);
  stage(1, 1);
  stage(2, 2);

  for (int tt = 0; tt < 12; tt += 4) {
    #pragma unroll
    for (int q = 0; q < 4; ++q) {
      const int kt = tt + q;
      WAITV8;
      BARRIER;
      SB0;
      stage((q + 3) & 3, kt + 3);
      phase(q);
    }
  }
  WAITV8; BARRIER; SB0; stage(3, 15); phase(0);
  WAITV8; BARRIER; SB0; phase(1);
  WAITV4; BARRIER; SB0; phase(2);
  WAITV0; BARRIER; SB0; phase(3);

  #pragma unroll
  for (int mi = 0; mi < 4; ++mi)
    #pragma unroll
    for (int ni = 0; ni < 2; ++ni) {
      int m = m0 + wm * 64 + mi * 16 + kg * 4;
      int n = n0 + wn * 32 + ni * 16 + lr;
      #pragma unroll
      for (int i = 0; i < 4; ++i)
        out[(size_t)(m + i) * D_MODEL + n] = acc[mi][ni][i];
    }
}

// ---------------------------------------------------------------------------
// Kernel 2: causal flash attention — R17 structure; exp2-domain softmax via
// RAW v_exp_f32 (__builtin_amdgcn_exp2f). log2e is pre-folded into Q by
// qkv8w, so P = exp2(S) needs exactly ONE VALU op (vs __expf's mul+exp;
// libm exp2f regressed to the precise OCML path — R19 post-mortem).
// Swapped-QK^T, packed b64 P-writes, scalar row-sum, balanced qt remap,
// KVBLK=64, double-buffered K/V via global_load_lds + XOR swizzle, 40 KB
// LDS (4 blocks/CU), XCD pin id%8 = bh%8.
// ---------------------------------------------------------------------------
__global__ __launch_bounds__(256) void attn_kernel(
    const u16* __restrict__ Qb, const u16* __restrict__ Kb,
    const u16* __restrict__ Vt, u16* __restrict__ AO)
{
  __shared__ u16 Ks[2][64 * 64];   // 16 KB
  __shared__ u16 Vs[2][64 * 64];   // 16 KB  (Vs[d][kv], chunk-swizzled)
  __shared__ u16 Ps[4][16 * 64];   // 8 KB, chunk8 ^ (row&7) swizzle
  const int t = threadIdx.x;
  const int bh = blockIdx.x;       // head -> XCD = bh % 8
  const int y = blockIdx.y;
  // balanced remap: family {y0, y0+8, y0+16, y0+24} -> qt {y0,15-y0,16+y0,31-y0}
  const int qt = (y < 8) ? y : (y < 16) ? (23 - y) : (y < 24) ? y : (55 - y);
  const int lane = t & 63, wv = t >> 6;
  const int kg = lane >> 4, lr = lane & 15;
  const int r8 = lane >> 3, c = lane & 7;
  const int b = bh >> 4, h = bh & (NH - 1);

  auto stage = [&](int buf, int kv0) {
    #pragma unroll
    for (int i = 0; i < 2; ++i) {
      int s = wv * 2 + i;
      int row = s * 8 + r8;                       // 0..63
      int sc = c ^ (row & 7);                     // pre-swizzled source chunk
      gload16(&Kb[((size_t)bh * SEQ + kv0 + row) * 64 + sc * 8], &Ks[buf][s * 512]);
      gload16(&Vt[((size_t)bh * 64 + row) * SEQ + kv0 + sc * 8], &Vs[buf][s * 512]);
    }
  };

  const int ntile = qt + 1;
  const int q0 = qt * 64;
  const int qg = q0 + wv * 16 + lr;   // this lane's q row (global)

  const size_t qrow = (size_t)bh * SEQ + qg;
  bf16x8 aq0 = ld8(&Qb[qrow * 64 + kg * 8]);        // Q pre-scaled 0.125*log2e
  bf16x8 aq1 = ld8(&Qb[qrow * 64 + 32 + kg * 8]);

  f32x4 of[4] = {};
  float rs = 0.f;

  stage(0, 0);
  int cur = 0;
  u16* ps = &Ps[wv][0];
  const int pwr = lr * 64;            // P row base (row = q local = lr)
  const int ch0 = kg ^ (lr & 7);      // chunk for k/kv 8kg..8kg+7
  const int ch1 = (4 + kg) ^ (lr & 7);

  for (int kt = 0; kt < ntile; ++kt) {
    const int kv0 = kt * 64;
    __syncthreads();               // drains staging of buf[cur]
    if (kt + 1 < ntile) stage(cur ^ 1, (kt + 1) * 64);

    // scores (swapped): S^T[kv][q] = K @ Q^T ; lane holds q=lr, kv=ct*16+kg*4+i
    const u16* kb = &Ks[cur][0];
    f32x4 sc4[4] = {};
    __builtin_amdgcn_s_setprio(1);
    #pragma unroll
    for (int ct = 0; ct < 4; ++ct) {
      sc4[ct] = MFMA(ld8(&kb[(ct * 16 + lr) * 64 + ch0 * 8]), aq0, sc4[ct]);
      sc4[ct] = MFMA(ld8(&kb[(ct * 16 + lr) * 64 + ch1 * 8]), aq1, sc4[ct]);
    }
    __builtin_amdgcn_s_setprio(0);

    // max-free softmax in exp2 domain: P = 2^S via raw v_exp_f32
    const bool domask = (kt == ntile - 1);
    #pragma unroll
    for (int ct = 0; ct < 4; ++ct) {
      #pragma unroll
      for (int i = 0; i < 4; ++i) {
        float e = __builtin_amdgcn_exp2f(sc4[ct][i]);
        if (domask && (kv0 + ct * 16 + kg * 4 + i > qg)) e = 0.f;
        sc4[ct][i] = e;
        rs += e;
      }
      u16x4v pw = { f2bf_hw(sc4[ct][0]), f2bf_hw(sc4[ct][1]),
                    f2bf_hw(sc4[ct][2]), f2bf_hw(sc4[ct][3]) };
      // kv_local = ct*16+kg*4 -> chunk8 = 2ct+(kg>>1), offset (kg&1)*4
      *(u16x4v*)&ps[pwr + (((2 * ct + (kg >> 1)) ^ (lr & 7)) * 8 + (kg & 1) * 4)] = pw;
    }

    bf16x8 pa0 = ld8(&ps[pwr + ch0 * 8]);
    bf16x8 pa1 = ld8(&ps[pwr + ch1 * 8]);

    // PV: A = P rows q, B = Vs rows d (Vs[d][kv]) -> C row=q(kg*4+i), col=d(lr)
    const u16* vb = &Vs[cur][0];
    __builtin_amdgcn_s_setprio(1);
    #pragma unroll
    for (int vt = 0; vt < 4; ++vt) {
      of[vt] = MFMA(pa0, ld8(&vb[(vt * 16 + lr) * 64 + ch0 * 8]), of[vt]);
      of[vt] = MFMA(pa1, ld8(&vb[(vt * 16 + lr) * 64 + ch1 * 8]), of[vt]);
    }
    __builtin_amdgcn_s_setprio(0);
    cur ^= 1;
  }

  // rs: per-lane partial for q = lr; reduce across the 4 kg-groups
  rs += __shfl_xor(rs, 16, 64);
  rs += __shfl_xor(rs, 32, 64);

  // of[vt][i] is q = kg*4+i -> fetch that q's denominator from lane kg*4+i
  #pragma unroll
  for (int i = 0; i < 4; ++i) {
    float inv = 1.0f / __shfl(rs, kg * 4 + i, 64);
    int s = q0 + wv * 16 + kg * 4 + i;
    size_t base = ((size_t)(b * SEQ + s)) * D_MODEL + h * 64 + lr;
    #pragma unroll
    for (int vt = 0; vt < 4; ++vt)
      AO[base + vt * 16] = f2bf_hw(of[vt][i] * inv);
  }
}

// ---------------------------------------------------------------------------
extern "C" void kernel_launch(void* const* d_in, const int* in_sizes, int n_in,
                              void* d_out, int out_size, void* d_ws, size_t ws_size,
                              hipStream_t stream) {
  const float* X  = (const float*)d_in[0];
  const float* Wq = (const float*)d_in[1];
  const float* Wk = (const float*)d_in[2];
  const float* Wv = (const float*)d_in[3];
  const float* Wo = (const float*)d_in[4];
  float* out = (float*)d_out;

  u16* Xb = (u16*)d_ws;
  u16* Wb = Xb + (size_t)4096 * 1024;
  u16* Qb = Wb + (size_t)4096 * 1024;
  u16* Kb = Qb + (size_t)4096 * 1024;
  u16* Vt = Kb + (size_t)4096 * 1024;
  u16* AO = Vt + (size_t)4096 * 1024;

  convert_kernel<<<2048, 256, 0, stream>>>(X, Wq, Wk, Wv, Wo, Xb, Wb);
  qkv8w<<<dim3(16, 12), 512, 0, stream>>>(Xb, Wb, Qb, Kb, Vt);
  attn_kernel<<<dim3(32, 32), 256, 0, stream>>>(Qb, Kb, Vt, AO);
  oproj8w<<<dim3(32, 8), 512, 0, stream>>>(AO, Wb + (size_t)3 * 1024 * 1024, out);
}

// Round 21
// 98.411 us; speedup vs baseline: 1.1684x; 1.0635x over previous
//
#include <hip/hip_runtime.h>

typedef unsigned short u16;
typedef unsigned u32;
typedef __bf16 bf16x8 __attribute__((ext_vector_type(8)));
typedef float f32x4 __attribute__((ext_vector_type(4)));
typedef u16 u16x8 __attribute__((ext_vector_type(8)));
typedef u16 u16x4v __attribute__((ext_vector_type(4)));

#define D_MODEL 1024
#define SEQ 2048
#define NB 2
#define NH 16

#define MFMA(a, b, c) __builtin_amdgcn_mfma_f32_16x16x32_bf16(a, b, c, 0, 0, 0)

__device__ __forceinline__ u16 f2bf(float f) {
  unsigned u = __builtin_bit_cast(unsigned, f);
  u += 0x7FFFu + ((u >> 16) & 1u);   // round-to-nearest-even
  return (u16)(u >> 16);
}

__device__ __forceinline__ u16 f2bf_hw(float f) {
  return __builtin_bit_cast(u16, (__bf16)f);
}

__device__ __forceinline__ bf16x8 ld8(const u16* p) {
  return __builtin_bit_cast(bf16x8, *(const u16x8*)p);
}

typedef const __attribute__((address_space(1))) unsigned gu32;
typedef __attribute__((address_space(3))) unsigned lu32;
__device__ __forceinline__ void gload16(const u16* g, u16* l) {
  // async global->LDS, 16B per lane; LDS dest = wave-uniform base + lane*16
  __builtin_amdgcn_global_load_lds((gu32*)g, (lu32*)l, 16, 0, 0);
}

#define WAITV8 asm volatile("s_waitcnt vmcnt(8)" ::: "memory")
#define WAITV4 asm volatile("s_waitcnt vmcnt(4)" ::: "memory")
#define WAITV0 asm volatile("s_waitcnt vmcnt(0)" ::: "memory")
#define BARRIER __builtin_amdgcn_s_barrier()
#define SB0 __builtin_amdgcn_sched_barrier(0)

// ---------------------------------------------------------------------------
// Kernel 0: fp32 -> bf16 convert of X and all four weight matrices.
// ---------------------------------------------------------------------------
__global__ __launch_bounds__(256) void convert_kernel(
    const float* __restrict__ X, const float* __restrict__ Wq,
    const float* __restrict__ Wk, const float* __restrict__ Wv,
    const float* __restrict__ Wo, u16* __restrict__ Xb, u16* __restrict__ Wb)
{
  const int NX4 = 1024 * 1024;
  const int NW4 = 256 * 1024;
  const int TOT = NX4 + 4 * NW4;
  for (int i = blockIdx.x * 256 + threadIdx.x; i < TOT; i += gridDim.x * 256) {
    const float* src;
    u16* dst;
    if (i < NX4) {
      src = X + (size_t)i * 4;
      dst = Xb + (size_t)i * 4;
    } else {
      int j = i - NX4;
      int w = j >> 18;
      int off = j & (NW4 - 1);
      const float* ws = (w == 0) ? Wq : (w == 1) ? Wk : (w == 2) ? Wv : Wo;
      src = ws + (size_t)off * 4;
      dst = Wb + (size_t)j * 4;
    }
    float4 v = *(const float4*)src;
    u16x4v o = { f2bf(v.x), f2bf(v.y), f2bf(v.z), f2bf(v.w) };
    *(u16x4v*)dst = o;
  }
}

// ---------------------------------------------------------------------------
// Kernel 1: QKV GEMM, 256x256 tile, 8 waves, BK=32, 4-buffer LDS rotation,
// one raw s_barrier per phase, counted vmcnt(8), compact-region XCD swizzle
// (R14 configuration — measured best).
// ---------------------------------------------------------------------------
__global__ __launch_bounds__(512, 2) void qkv8w(
    const u16* __restrict__ A, const u16* __restrict__ B,
    u16* __restrict__ Qb, u16* __restrict__ Kb, u16* __restrict__ Vt)
{
  __shared__ u16 As[4][8192];   // 4 x 16 KB
  __shared__ u16 Bs[4][8192];   // 4 x 16 KB  -> 128 KB total
  const int t = threadIdx.x;
  const int lane = t & 63, w = t >> 6;
  const int wm = w >> 2, wn = w & 3;

  // compact-region XCD swizzle: XCD = lid%8 -> 4x6 block region
  const int lid = blockIdx.x + 16 * blockIdx.y;   // 0..191
  const int xcd = lid & 7;
  const int k = lid >> 3;                          // 0..23
  const int bx = (xcd >> 1) * 4 + (k & 3);         // 0..15
  const int by = (xcd & 1) * 6 + (k >> 2);         // 0..11

  const int m0 = bx * 256;
  const int kg = lane >> 4, lr = lane & 15;
  const int rp = lr >> 1, hf = lr & 1;
  const int xr = (((hf * 4 + kg) ^ rp) * 8);

  const int lc = (lane & 7) ^ (lane >> 3);
  const int ghalf = lc >> 2, kc = lc & 3;
  const int n0 = by * 256;

  f32x4 acc[8][4] = {};

  auto stage = [&](int buf, int kt) {
    #pragma unroll
    for (int j = 0; j < 2; ++j) {
      int g = (j * 64 + w * 8 + (lane >> 3)) * 2 + ghalf;
      gload16(&A[(size_t)(m0 + g) * 1024 + kt * 32 + kc * 8],
              &As[buf][(j * 8 + w) * 512]);
      gload16(&B[(size_t)(n0 + g) * 1024 + kt * 32 + kc * 8],
              &Bs[buf][(j * 8 + w) * 512]);
    }
  };

  auto phase = [&](int buf) {
    const u16* as = &As[buf][0];
    const u16* bs = &Bs[buf][0];
    bf16x8 a[8], b[4];
    #pragma unroll
    for (int mi = 0; mi < 8; ++mi)
      a[mi] = ld8(&as[(wm * 64 + mi * 8 + rp) * 64 + xr]);
    #pragma unroll
    for (int ni = 0; ni < 4; ++ni)
      b[ni] = ld8(&bs[(wn * 32 + ni * 8 + rp) * 64 + xr]);
    __builtin_amdgcn_s_setprio(1);
    #pragma unroll
    for (int mi = 0; mi < 8; ++mi)
      #pragma unroll
      for (int ni = 0; ni < 4; ++ni)
        acc[mi][ni] = MFMA(a[mi], b[ni], acc[mi][ni]);
    __builtin_amdgcn_s_setprio(0);
  };

  stage(0, 0);
  stage(1, 1);
  stage(2, 2);

  for (int tt = 0; tt < 28; tt += 4) {
    #pragma unroll
    for (int q = 0; q < 4; ++q) {
      const int kt = tt + q;
      WAITV8;
      BARRIER;
      SB0;
      stage((q + 3) & 3, kt + 3);
      phase(q);
    }
  }
  WAITV8; BARRIER; SB0; stage(3, 31); phase(0);
  WAITV8; BARRIER; SB0; phase(1);
  WAITV4; BARRIER; SB0; phase(2);
  WAITV0; BARRIER; SB0; phase(3);

  // epilogue: scatter to Q/K/V.  C/D frag: row = kg*4+i, col = lr.
  const int zby = by >> 2;              // 0=Q, 1=K, 2=V
  const int nl0 = (by & 3) * 256;
  const float scl = (zby == 0) ? 0.125f : 1.0f; // fold 1/sqrt(d_k) into Q
  #pragma unroll
  for (int mi = 0; mi < 8; ++mi) {
    #pragma unroll
    for (int ni = 0; ni < 4; ++ni) {
      int m = m0 + wm * 128 + mi * 16 + kg * 4;
      int nl = nl0 + wn * 64 + ni * 16 + lr;
      int bb = m >> 11, s = m & (SEQ - 1);
      int h = nl >> 6, dk = nl & 63;
      size_t bh = (size_t)(bb * NH + h);
      if (zby == 2) {
        u16x4v v = { f2bf(acc[mi][ni][0]), f2bf(acc[mi][ni][1]),
                     f2bf(acc[mi][ni][2]), f2bf(acc[mi][ni][3]) };
        *(u16x4v*)&Vt[(bh * 64 + dk) * SEQ + s] = v;
      } else {
        u16* dst = (zby == 0 ? Qb : Kb) + ((bh * SEQ + s) * 64 + dk);
        #pragma unroll
        for (int i = 0; i < 4; ++i) dst[(size_t)i * 64] = f2bf(acc[mi][ni][i] * scl);
      }
    }
  }
}

// ---------------------------------------------------------------------------
// Kernel 3: output projection — qkv8w schedule: 128x128 tile, 8 waves,
// BK=64, 16 phases, 4-buffer LDS rotation, counted vmcnt(8) (R16 config).
// ---------------------------------------------------------------------------
__global__ __launch_bounds__(512, 2) void oproj8w(
    const u16* __restrict__ A, const u16* __restrict__ B,
    float* __restrict__ out)
{
  __shared__ u16 As[4][8192];   // 4 x 16 KB (128 rows x 64 K, chunk-XOR swz)
  __shared__ u16 Bs[4][8192];
  const int t = threadIdx.x;
  const int lane = t & 63, w = t >> 6;
  const int wm = w >> 2, wn = w & 3;      // 2 x 4 wave grid
  const int m0 = blockIdx.x * 128;
  const int n0 = blockIdx.y * 128;
  const int kg = lane >> 4, lr = lane & 15;

  const int srow = lane >> 3;
  const int lc = (lane & 7) ^ srow;

  f32x4 acc[4][2] = {};

  auto stage = [&](int buf, int kt) {
    #pragma unroll
    for (int j = 0; j < 2; ++j) {
      int r = (j * 8 + w) * 8 + srow;     // 0..127
      gload16(&A[(size_t)(m0 + r) * 1024 + kt * 64 + lc * 8],
              &As[buf][(j * 8 + w) * 512]);
      gload16(&B[(size_t)(n0 + r) * 1024 + kt * 64 + lc * 8],
              &Bs[buf][(j * 8 + w) * 512]);
    }
  };

  auto phase = [&](int buf) {
    const u16* as = &As[buf][0];
    const u16* bs = &Bs[buf][0];
    #pragma unroll
    for (int kh = 0; kh < 2; ++kh) {
      bf16x8 a[4], b[2];
      #pragma unroll
      for (int mi = 0; mi < 4; ++mi) {
        int row = wm * 64 + mi * 16 + lr;
        int ch = (kh * 4 + kg) ^ (row & 7);
        a[mi] = ld8(&as[row * 64 + ch * 8]);
      }
      #pragma unroll
      for (int ni = 0; ni < 2; ++ni) {
        int row = wn * 32 + ni * 16 + lr;
        int ch = (kh * 4 + kg) ^ (row & 7);
        b[ni] = ld8(&bs[row * 64 + ch * 8]);
      }
      __builtin_amdgcn_s_setprio(1);
      #pragma unroll
      for (int mi = 0; mi < 4; ++mi)
        #pragma unroll
        for (int ni = 0; ni < 2; ++ni)
          acc[mi][ni] = MFMA(a[mi], b[ni], acc[mi][ni]);
      __builtin_amdgcn_s_setprio(0);
    }
  };

  stage(0, 0);
  stage(1, 1);
  stage(2, 2);

  for (int tt = 0; tt < 12; tt += 4) {
    #pragma unroll
    for (int q = 0; q < 4; ++q) {
      const int kt = tt + q;
      WAITV8;
      BARRIER;
      SB0;
      stage((q + 3) & 3, kt + 3);
      phase(q);
    }
  }
  WAITV8; BARRIER; SB0; stage(3, 15); phase(0);
  WAITV8; BARRIER; SB0; phase(1);
  WAITV4; BARRIER; SB0; phase(2);
  WAITV0; BARRIER; SB0; phase(3);

  #pragma unroll
  for (int mi = 0; mi < 4; ++mi)
    #pragma unroll
    for (int ni = 0; ni < 2; ++ni) {
      int m = m0 + wm * 64 + mi * 16 + kg * 4;
      int n = n0 + wn * 32 + ni * 16 + lr;
      #pragma unroll
      for (int i = 0; i < 4; ++i)
        out[(size_t)(m + i) * D_MODEL + n] = acc[mi][ni][i];
    }
}

// ---------------------------------------------------------------------------
// Kernel 2: causal flash attention — R17 measured-best state (41.1 us).
// Swapped-QK^T (S^T = K@Q^T): lane holds q=lr, kv=ct*16+kg*4+i -> packed
// b64 P-writes, scalar per-lane row-sum via __expf, 2-step shfl_xor reduce
// + per-q shuffle epilogue. Balanced qt remap (co-resident family sums 66).
// KVBLK=64, double-buffered K/V via global_load_lds + XOR swizzle, 40 KB
// LDS (4 blocks/CU), XCD pin id%8 = bh%8.
// ---------------------------------------------------------------------------
__global__ __launch_bounds__(256) void attn_kernel(
    const u16* __restrict__ Qb, const u16* __restrict__ Kb,
    const u16* __restrict__ Vt, u16* __restrict__ AO)
{
  __shared__ u16 Ks[2][64 * 64];   // 16 KB
  __shared__ u16 Vs[2][64 * 64];   // 16 KB  (Vs[d][kv], chunk-swizzled)
  __shared__ u16 Ps[4][16 * 64];   // 8 KB, chunk8 ^ (row&7) swizzle
  const int t = threadIdx.x;
  const int bh = blockIdx.x;       // head -> XCD = bh % 8
  const int y = blockIdx.y;
  // balanced remap: family {y0, y0+8, y0+16, y0+24} -> qt {y0,15-y0,16+y0,31-y0}
  const int qt = (y < 8) ? y : (y < 16) ? (23 - y) : (y < 24) ? y : (55 - y);
  const int lane = t & 63, wv = t >> 6;
  const int kg = lane >> 4, lr = lane & 15;
  const int r8 = lane >> 3, c = lane & 7;
  const int b = bh >> 4, h = bh & (NH - 1);

  auto stage = [&](int buf, int kv0) {
    #pragma unroll
    for (int i = 0; i < 2; ++i) {
      int s = wv * 2 + i;
      int row = s * 8 + r8;                       // 0..63
      int sc = c ^ (row & 7);                     // pre-swizzled source chunk
      gload16(&Kb[((size_t)bh * SEQ + kv0 + row) * 64 + sc * 8], &Ks[buf][s * 512]);
      gload16(&Vt[((size_t)bh * 64 + row) * SEQ + kv0 + sc * 8], &Vs[buf][s * 512]);
    }
  };

  const int ntile = qt + 1;
  const int q0 = qt * 64;
  const int qg = q0 + wv * 16 + lr;   // this lane's q row (global)

  const size_t qrow = (size_t)bh * SEQ + qg;
  bf16x8 aq0 = ld8(&Qb[qrow * 64 + kg * 8]);        // Q pre-scaled by 0.125
  bf16x8 aq1 = ld8(&Qb[qrow * 64 + 32 + kg * 8]);

  f32x4 of[4] = {};
  float rs = 0.f;

  stage(0, 0);
  int cur = 0;
  u16* ps = &Ps[wv][0];
  const int pwr = lr * 64;            // P row base (row = q local = lr)
  const int ch0 = kg ^ (lr & 7);      // chunk for k/kv 8kg..8kg+7
  const int ch1 = (4 + kg) ^ (lr & 7);

  for (int kt = 0; kt < ntile; ++kt) {
    const int kv0 = kt * 64;
    __syncthreads();               // drains staging of buf[cur]
    if (kt + 1 < ntile) stage(cur ^ 1, (kt + 1) * 64);

    // scores (swapped): S^T[kv][q] = K @ Q^T ; lane holds q=lr, kv=ct*16+kg*4+i
    const u16* kb = &Ks[cur][0];
    f32x4 sc4[4] = {};
    __builtin_amdgcn_s_setprio(1);
    #pragma unroll
    for (int ct = 0; ct < 4; ++ct) {
      sc4[ct] = MFMA(ld8(&kb[(ct * 16 + lr) * 64 + ch0 * 8]), aq0, sc4[ct]);
      sc4[ct] = MFMA(ld8(&kb[(ct * 16 + lr) * 64 + ch1 * 8]), aq1, sc4[ct]);
    }
    __builtin_amdgcn_s_setprio(0);

    // max-free softmax: P = exp(S), masked -> 0; packed b64 P-writes
    const bool domask = (kt == ntile - 1);
    #pragma unroll
    for (int ct = 0; ct < 4; ++ct) {
      #pragma unroll
      for (int i = 0; i < 4; ++i) {
        float e = __expf(sc4[ct][i]);
        if (domask && (kv0 + ct * 16 + kg * 4 + i > qg)) e = 0.f;
        sc4[ct][i] = e;
        rs += e;
      }
      u16x4v pw = { f2bf_hw(sc4[ct][0]), f2bf_hw(sc4[ct][1]),
                    f2bf_hw(sc4[ct][2]), f2bf_hw(sc4[ct][3]) };
      // kv_local = ct*16+kg*4 -> chunk8 = 2ct+(kg>>1), offset (kg&1)*4
      *(u16x4v*)&ps[pwr + (((2 * ct + (kg >> 1)) ^ (lr & 7)) * 8 + (kg & 1) * 4)] = pw;
    }

    bf16x8 pa0 = ld8(&ps[pwr + ch0 * 8]);
    bf16x8 pa1 = ld8(&ps[pwr + ch1 * 8]);

    // PV: A = P rows q, B = Vs rows d (Vs[d][kv]) -> C row=q(kg*4+i), col=d(lr)
    const u16* vb = &Vs[cur][0];
    __builtin_amdgcn_s_setprio(1);
    #pragma unroll
    for (int vt = 0; vt < 4; ++vt) {
      of[vt] = MFMA(pa0, ld8(&vb[(vt * 16 + lr) * 64 + ch0 * 8]), of[vt]);
      of[vt] = MFMA(pa1, ld8(&vb[(vt * 16 + lr) * 64 + ch1 * 8]), of[vt]);
    }
    __builtin_amdgcn_s_setprio(0);
    cur ^= 1;
  }

  // rs: per-lane partial for q = lr; reduce across the 4 kg-groups
  rs += __shfl_xor(rs, 16, 64);
  rs += __shfl_xor(rs, 32, 64);

  // of[vt][i] is q = kg*4+i -> fetch that q's denominator from lane kg*4+i
  #pragma unroll
  for (int i = 0; i < 4; ++i) {
    float inv = 1.0f / __shfl(rs, kg * 4 + i, 64);
    int s = q0 + wv * 16 + kg * 4 + i;
    size_t base = ((size_t)(b * SEQ + s)) * D_MODEL + h * 64 + lr;
    #pragma unroll
    for (int vt = 0; vt < 4; ++vt)
      AO[base + vt * 16] = f2bf_hw(of[vt][i] * inv);
  }
}

// ---------------------------------------------------------------------------
extern "C" void kernel_launch(void* const* d_in, const int* in_sizes, int n_in,
                              void* d_out, int out_size, void* d_ws, size_t ws_size,
                              hipStream_t stream) {
  const float* X  = (const float*)d_in[0];
  const float* Wq = (const float*)d_in[1];
  const float* Wk = (const float*)d_in[2];
  const float* Wv = (const float*)d_in[3];
  const float* Wo = (const float*)d_in[4];
  float* out = (float*)d_out;

  u16* Xb = (u16*)d_ws;
  u16* Wb = Xb + (size_t)4096 * 1024;
  u16* Qb = Wb + (size_t)4096 * 1024;
  u16* Kb = Qb + (size_t)4096 * 1024;
  u16* Vt = Kb + (size_t)4096 * 1024;
  u16* AO = Vt + (size_t)4096 * 1024;

  convert_kernel<<<2048, 256, 0, stream>>>(X, Wq, Wk, Wv, Wo, Xb, Wb);
  qkv8w<<<dim3(16, 12), 512, 0, stream>>>(Xb, Wb, Qb, Kb, Vt);
  attn_kernel<<<dim3(32, 32), 256, 0, stream>>>(Qb, Kb, Vt, AO);
  oproj8w<<<dim3(32, 8), 512, 0, stream>>>(AO, Wb + (size_t)3 * 1024 * 1024, out);
}